// Round 9
// baseline (318.059 us; speedup 1.0000x reference)
//
#include <hip/hip_runtime.h>

// ---------------- workspace layout (indices into uint32 view) ---------------
// wsu[0] = min key, wsu[1] = max key (monotonic uint mapping of float)
// wsu[2..257] = hist[256]
// byte offset 4096: gray[npix]
static constexpr int HIST_OFF = 2;
static constexpr size_t GRAY_BYTE_OFF = 4096;

typedef float nfloat4 __attribute__((ext_vector_type(4)));

// async global->LDS DMA, 16 B per lane; LDS dst = wave-uniform base + lane*16
#define GLOAD_LDS16(gp, lp)                                                    \
    __builtin_amdgcn_global_load_lds(                                          \
        (const __attribute__((address_space(1))) void*)(gp),                   \
        (__attribute__((address_space(3))) void*)(lp), 16, 0, 0)

__device__ __forceinline__ unsigned fkey(float x) {
    unsigned u = __float_as_uint(x);
    return (u & 0x80000000u) ? ~u : (u | 0x80000000u);
}
__device__ __forceinline__ float keyf(unsigned k) {
    return (k & 0x80000000u) ? __uint_as_float(k & 0x7FFFFFFFu)
                             : __uint_as_float(~k);
}
// gray = ((r*wr + g*wg) + b*wb), strict f32 rounding, NO fma contraction
__device__ __forceinline__ float gray1(float r, float g, float b) {
    float t0 = __fmul_rn(r, 0.2989f);
    float t1 = __fmul_rn(g, 0.5870f);
    float t2 = __fmul_rn(b, 0.1140f);
    return __fadd_rn(__fadd_rn(t0, t1), t2);
}
__device__ __forceinline__ unsigned aload(const unsigned* p) {
    return __hip_atomic_load(p, __ATOMIC_RELAXED, __HIP_MEMORY_SCOPE_AGENT);
}

// Edges phase, recomputed redundantly (bit-identical everywhere):
// delta = (vmax-vmin)/256 exact; eds[i] = vmin + i*delta; eds[256] = vmax.
__device__ __forceinline__ void build_edges(float* eds, float vmin, float vmax,
                                            float delta) {
    if (threadIdx.x < 256)
        eds[threadIdx.x] =
            __fadd_rn(vmin, __fmul_rn((float)threadIdx.x, delta));
    if (threadIdx.x == 0) eds[256] = vmax;
}

// Serial Otsu scan, numpy-cumsum order (thread 0 of a block).
__device__ __forceinline__ float otsu_scan(const float* histf,
                                           const float* centers, float* w2a,
                                           float* s2a) {
    float w = 0.0f, s = 0.0f;
    for (int t = 255; t >= 0; --t) {
        w = __fadd_rn(w, histf[t]);
        s = __fadd_rn(s, __fmul_rn(histf[t], centers[t]));
        w2a[t] = w;
        s2a[t] = s;
    }
    float w1 = 0.0f, s1 = 0.0f, best = -1.0f;
    int bidx = 0;
    for (int t = 0; t < 255; ++t) {
        w1 = __fadd_rn(w1, histf[t]);
        s1 = __fadd_rn(s1, __fmul_rn(histf[t], centers[t]));
        float m1 = __fdiv_rn(s1, fmaxf(w1, 1.0f));
        float m2 = __fdiv_rn(s2a[t + 1], fmaxf(w2a[t + 1], 1.0f));
        float d  = __fsub_rn(m1, m2);
        float v  = __fmul_rn(__fmul_rn(w1, w2a[t + 1]), __fmul_rn(d, d));
        if (v > best) { best = v; bidx = t; }     // first max, like argmax
    }
    return centers[bidx];
}

__global__ void init_kernel(unsigned* __restrict__ wsu) {
    int i = threadIdx.x;
    if (i < 256) wsu[HIST_OFF + i] = 0u;
    if (i == 0) { wsu[0] = 0xFFFFFFFFu; wsu[1] = 0u; }
}

// ---------- gray pass: async global->LDS DMA, per-wave double buffer --------
// (R8; ~65 us — read throughput is platform-capped, structure-insensitive)
__global__ void __launch_bounds__(256)
gray_minmax_async(const float* __restrict__ in, float* __restrict__ gray,
                  unsigned* __restrict__ wsu, int npix4) {
    __shared__ float4 sbuf[4][2][192];
    __shared__ unsigned smn[4], smx[4];
    const float4* in4 = (const float4*)in;
    float4* gray4 = (float4*)gray;
    const int lane = threadIdx.x & 63;
    const int w = threadIdx.x >> 6;
    const int gw = blockIdx.x * 4 + w;
    const size_t wbase4 = (size_t)gw * 768;
    unsigned mn = 0xFFFFFFFFu, mx = 0u;

#pragma unroll
    for (int k = 0; k < 3; ++k)
        GLOAD_LDS16(in4 + wbase4 + 64 * k + lane, &sbuf[w][0][64 * k]);

#pragma unroll
    for (int t = 0; t < 4; ++t) {
        const int cb = t & 1;
        if (t < 3) {
#pragma unroll
            for (int k = 0; k < 3; ++k)
                GLOAD_LDS16(in4 + wbase4 + (size_t)(t + 1) * 192 + 64 * k + lane,
                            &sbuf[w][cb ^ 1][64 * k]);
            __builtin_amdgcn_s_waitcnt(0x0F73);   // vmcnt(3)
        } else {
            __builtin_amdgcn_s_waitcnt(0x0F71);   // vmcnt(1)
        }
        float4 c0 = sbuf[w][cb][3 * lane + 0];
        float4 c1 = sbuf[w][cb][3 * lane + 1];
        float4 c2 = sbuf[w][cb][3 * lane + 2];
        float g0 = gray1(c0.x, c0.y, c0.z);
        float g1 = gray1(c0.w, c1.x, c1.y);
        float g2 = gray1(c1.z, c1.w, c2.x);
        float g3 = gray1(c2.y, c2.z, c2.w);
        gray4[(size_t)gw * 256 + t * 64 + lane] = make_float4(g0, g1, g2, g3);
        unsigned k0 = fkey(g0), k1 = fkey(g1), k2 = fkey(g2), k3 = fkey(g3);
        mn = min(mn, min(min(k0, k1), min(k2, k3)));
        mx = max(mx, max(max(k0, k1), max(k2, k3)));
    }
    for (int off = 32; off > 0; off >>= 1) {
        mn = min(mn, (unsigned)__shfl_xor((int)mn, off, 64));
        mx = max(mx, (unsigned)__shfl_xor((int)mx, off, 64));
    }
    if (lane == 0) { smn[w] = mn; smx[w] = mx; }
    __syncthreads();
    if (threadIdx.x == 0) {
        mn = min(min(smn[0], smn[1]), min(smn[2], smn[3]));
        mx = max(max(smx[0], smx[1]), max(smx[2], smx[3]));
        atomicMin(&wsu[0], mn);
        atomicMax(&wsu[1], mx);
    }
}

// generic fallback (any size)
__global__ void __launch_bounds__(256)
gray_minmax_generic(const float* __restrict__ in, float* __restrict__ gray,
                    unsigned* __restrict__ wsu, int npix4) {
    __shared__ unsigned smn[4], smx[4];
    const float4* in4 = (const float4*)in;
    const int stride = gridDim.x * blockDim.x;
    unsigned mn = 0xFFFFFFFFu, mx = 0u;
    for (int t = blockIdx.x * blockDim.x + threadIdx.x; t < npix4; t += stride) {
        const float4* p = in4 + (size_t)t * 3;
        float4 c0 = p[0], c1 = p[1], c2 = p[2];
        float g0 = gray1(c0.x, c0.y, c0.z);
        float g1 = gray1(c0.w, c1.x, c1.y);
        float g2 = gray1(c1.z, c1.w, c2.x);
        float g3 = gray1(c2.y, c2.z, c2.w);
        ((float4*)gray)[t] = make_float4(g0, g1, g2, g3);
        unsigned k0 = fkey(g0), k1 = fkey(g1), k2 = fkey(g2), k3 = fkey(g3);
        mn = min(mn, min(min(k0, k1), min(k2, k3)));
        mx = max(mx, max(max(k0, k1), max(k2, k3)));
    }
    for (int off = 32; off > 0; off >>= 1) {
        mn = min(mn, (unsigned)__shfl_xor((int)mn, off, 64));
        mx = max(mx, (unsigned)__shfl_xor((int)mx, off, 64));
    }
    int wave = threadIdx.x >> 6;
    if ((threadIdx.x & 63) == 0) { smn[wave] = mn; smx[wave] = mx; }
    __syncthreads();
    if (threadIdx.x == 0) {
        mn = min(min(smn[0], smn[1]), min(smn[2], smn[3]));
        mx = max(max(smx[0], smx[1]), max(smx[2], smx[3]));
        atomicMin(&wsu[0], mn);
        atomicMax(&wsu[1], mx);
    }
}

// ---------- hist (+ folded edges): 8-deep coalesced loads, LDS hist ---------
__global__ void __launch_bounds__(256)
hist_kernel(const float* __restrict__ gray, unsigned* __restrict__ wsu,
            int npix4) {
    __shared__ float eds[257];
    __shared__ unsigned lh[256];
    __shared__ unsigned skey[2];
    if (threadIdx.x == 0) { skey[0] = aload(&wsu[0]); skey[1] = aload(&wsu[1]); }
    __syncthreads();
    const float vmin = keyf(skey[0]);
    const float vmax = keyf(skey[1]);
    const float delta = __fdiv_rn(__fsub_rn(vmax, vmin), 256.0f);
    const float invd = (delta > 0.0f) ? __fdiv_rn(1.0f, delta) : 0.0f;
    build_edges(eds, vmin, vmax, delta);
    if (threadIdx.x < 256) lh[threadIdx.x] = 0u;
    __syncthreads();

    const int stride = gridDim.x * blockDim.x;
    const int base = blockIdx.x * blockDim.x + threadIdx.x;
    if (base + 7 * stride < npix4) {
        float4 g[8];
#pragma unroll
        for (int j = 0; j < 8; ++j)
            g[j] = ((const float4*)gray)[base + j * stride];
#pragma unroll
        for (int j = 0; j < 8; ++j) {
            float xs[4] = {g[j].x, g[j].y, g[j].z, g[j].w};
#pragma unroll
            for (int i = 0; i < 4; ++i) {
                float x = xs[i];
                int b = (int)(__fmul_rn(__fsub_rn(x, vmin), invd));
                b = b < 0 ? 0 : (b > 255 ? 255 : b);
                while (b < 255 && x >= eds[b + 1]) ++b;   // exact searchsorted
                while (b > 0 && x < eds[b]) --b;
                atomicAdd(&lh[b], 1u);
            }
        }
    } else {
        for (int t = base; t < npix4; t += stride) {
            float4 g4 = ((const float4*)gray)[t];
            float xs[4] = {g4.x, g4.y, g4.z, g4.w};
#pragma unroll
            for (int i = 0; i < 4; ++i) {
                float x = xs[i];
                int b = (int)(__fmul_rn(__fsub_rn(x, vmin), invd));
                b = b < 0 ? 0 : (b > 255 ? 255 : b);
                while (b < 255 && x >= eds[b + 1]) ++b;
                while (b > 0 && x < eds[b]) --b;
                atomicAdd(&lh[b], 1u);
            }
        }
    }
    __syncthreads();
    if (threadIdx.x < 256 && lh[threadIdx.x] != 0u)
        atomicAdd(&wsu[HIST_OFF + threadIdx.x], lh[threadIdx.x]);
}

// ---------- binarize (+ folded otsu): loads first, scan hidden behind them --
__global__ void __launch_bounds__(256)
binarize_fast(const float* __restrict__ gray, const unsigned* __restrict__ wsu,
              float* __restrict__ out, int npix4) {
    __shared__ float eds[257], histf[256], centers[256], w2a[256], s2a[256];
    __shared__ unsigned skey[2];
    __shared__ float sthr;
    const nfloat4* gray4 = (const nfloat4*)gray;
    nfloat4* out4 = (nfloat4*)out;
    const int lane = threadIdx.x & 63;
    const int gw = (blockIdx.x * blockDim.x + threadIdx.x) >> 6;
    const int ma = lane / 3,         qa = lane % 3;
    const int mb = (64 + lane) / 3,  qb = (64 + lane) % 3;
    const int mc = (128 + lane) / 3, qc = (128 + lane) % 3;

    // 1) issue all gray loads first (independent of threshold)
    nfloat4 g[4];
    bool full[4];
#pragma unroll
    for (int r = 0; r < 4; ++r) {
        int gbase = gw * 256 + r * 64;
        full[r] = (gbase + 64 <= npix4);
        if (full[r]) g[r] = gray4[gbase + lane];
        else {
            int t = gbase + lane;
            if (t < npix4) {
                // tail handled per-group below; load pieces now
                g[r].x = gray[(size_t)t * 4 + 0];
                g[r].y = gray[(size_t)t * 4 + 1];
                g[r].z = gray[(size_t)t * 4 + 2];
                g[r].w = gray[(size_t)t * 4 + 3];
            }
        }
    }

    // 2) edges + otsu scan while loads are in flight
    if (threadIdx.x == 0) { skey[0] = aload(&wsu[0]); skey[1] = aload(&wsu[1]); }
    __syncthreads();
    const float vmin = keyf(skey[0]);
    const float vmax = keyf(skey[1]);
    const float delta = __fdiv_rn(__fsub_rn(vmax, vmin), 256.0f);
    build_edges(eds, vmin, vmax, delta);
    if (threadIdx.x < 256)
        histf[threadIdx.x] = (float)aload(&wsu[HIST_OFF + threadIdx.x]);
    __syncthreads();
    if (threadIdx.x < 256)
        centers[threadIdx.x] =
            __fmul_rn(__fadd_rn(eds[threadIdx.x], eds[threadIdx.x + 1]), 0.5f);
    __syncthreads();
    if (threadIdx.x == 0) sthr = otsu_scan(histf, centers, w2a, s2a);
    __syncthreads();
    const float thr = sthr;

    // 3) compare + lane-exchange + unit-stride full-line NT stores
#pragma unroll
    for (int r = 0; r < 4; ++r) {
        const int gbase = gw * 256 + r * 64;
        if (full[r]) {
            unsigned u = (g[r].x > thr ? 1u : 0u) |
                         (g[r].y > thr ? 0x100u : 0u) |
                         (g[r].z > thr ? 0x10000u : 0u) |
                         (g[r].w > thr ? 0x1000000u : 0u);
            const int rb = 3 * gbase;
#pragma unroll
            for (int k = 0; k < 3; ++k) {
                int m = (k == 0) ? ma : (k == 1) ? mb : mc;
                int q = (k == 0) ? qa : (k == 1) ? qb : qc;
                unsigned w = (unsigned)__builtin_amdgcn_ds_bpermute(4 * m,
                                                                    (int)u);
                float h0 = (w & 0xffu)       ? 1.0f : 0.0f;
                float h1 = (w & 0xff00u)     ? 1.0f : 0.0f;
                float h2 = (w & 0xff0000u)   ? 1.0f : 0.0f;
                float h3 = (w & 0xff000000u) ? 1.0f : 0.0f;
                nfloat4 o;
                o.x = (q == 0) ? h0 : (q == 1) ? h1 : h2;
                o.y = (q == 0) ? h0 : (q == 1) ? h1 : h3;
                o.z = (q == 0) ? h0 : (q == 1) ? h2 : h3;
                o.w = (q == 0) ? h1 : (q == 1) ? h2 : h3;
                __builtin_nontemporal_store(o, &out4[rb + 64 * k + lane]);
            }
        } else {
            int t = gbase + lane;
            if (t < npix4) {
                float b0 = (g[r].x > thr) ? 1.0f : 0.0f;
                float b1 = (g[r].y > thr) ? 1.0f : 0.0f;
                float b2 = (g[r].z > thr) ? 1.0f : 0.0f;
                float b3 = (g[r].w > thr) ? 1.0f : 0.0f;
                nfloat4* o = out4 + (size_t)t * 3;
                __builtin_nontemporal_store((nfloat4){b0, b0, b0, b1}, &o[0]);
                __builtin_nontemporal_store((nfloat4){b1, b1, b2, b2}, &o[1]);
                __builtin_nontemporal_store((nfloat4){b2, b3, b3, b3}, &o[2]);
            }
        }
    }
}

extern "C" void kernel_launch(void* const* d_in, const int* in_sizes, int n_in,
                              void* d_out, int out_size, void* d_ws,
                              size_t ws_size, hipStream_t stream) {
    const float* in = (const float*)d_in[0];
    float* out = (float*)d_out;
    int npix  = out_size / 3;
    int npix4 = npix / 4;
    unsigned* wsu = (unsigned*)d_ws;
    float* gray = (float*)((char*)d_ws + GRAY_BYTE_OFF);

    hipLaunchKernelGGL(init_kernel, dim3(1), dim3(256), 0, stream, wsu);
    if (npix4 % 1024 == 0) {
        hipLaunchKernelGGL(gray_minmax_async, dim3(npix4 / 1024), dim3(256), 0,
                           stream, in, gray, wsu, npix4);
    } else {
        hipLaunchKernelGGL(gray_minmax_generic, dim3(2048), dim3(256), 0,
                           stream, in, gray, wsu, npix4);
    }
    hipLaunchKernelGGL(hist_kernel, dim3(1024), dim3(256), 0, stream,
                       gray, wsu, npix4);
    hipLaunchKernelGGL(binarize_fast, dim3((npix4 + 1023) / 1024), dim3(256),
                       0, stream, gray, wsu, out, npix4);
}

// Round 10
// 284.317 us; speedup vs baseline: 1.1187x; 1.1187x over previous
//
#include <hip/hip_runtime.h>

// ---------------- workspace layout -----------------------------------------
// wsu[0] = min key, wsu[1] = max key (monotonic uint mapping of float)
// wsu[2..257] = hist[256]
// wsu[258] = bidx (argmax bin), wsf[259] = threshold (float)
// byte 4096:                gray[npix]  (f32)
// byte 4096 + npix*4:       codes[npix] (u8 bin index)
static constexpr int HIST_OFF   = 2;
static constexpr int BIDX_OFF   = 258;
static constexpr int THRESH_OFF = 259;
static constexpr size_t GRAY_BYTE_OFF = 4096;

typedef float nfloat4 __attribute__((ext_vector_type(4)));

// async global->LDS DMA, 16 B per lane; LDS dst = wave-uniform base + lane*16
#define GLOAD_LDS16(gp, lp)                                                    \
    __builtin_amdgcn_global_load_lds(                                          \
        (const __attribute__((address_space(1))) void*)(gp),                   \
        (__attribute__((address_space(3))) void*)(lp), 16, 0, 0)

__device__ __forceinline__ unsigned fkey(float x) {
    unsigned u = __float_as_uint(x);
    return (u & 0x80000000u) ? ~u : (u | 0x80000000u);
}
__device__ __forceinline__ float keyf(unsigned k) {
    return (k & 0x80000000u) ? __uint_as_float(k & 0x7FFFFFFFu)
                             : __uint_as_float(~k);
}
// gray = ((r*wr + g*wg) + b*wb), strict f32 rounding, NO fma contraction
__device__ __forceinline__ float gray1(float r, float g, float b) {
    float t0 = __fmul_rn(r, 0.2989f);
    float t1 = __fmul_rn(g, 0.5870f);
    float t2 = __fmul_rn(b, 0.1140f);
    return __fadd_rn(__fadd_rn(t0, t1), t2);
}
__device__ __forceinline__ unsigned aload(const unsigned* p) {
    return __hip_atomic_load(p, __ATOMIC_RELAXED, __HIP_MEMORY_SCOPE_AGENT);
}

__global__ void init_kernel(unsigned* __restrict__ wsu) {
    int i = threadIdx.x;
    if (i < 256) wsu[HIST_OFF + i] = 0u;
    if (i == 0) { wsu[0] = 0xFFFFFFFFu; wsu[1] = 0u; }
}

// ---------- gray pass: async global->LDS DMA, per-wave double buffer (R8) ---
__global__ void __launch_bounds__(256)
gray_minmax_async(const float* __restrict__ in, float* __restrict__ gray,
                  unsigned* __restrict__ wsu, int npix4) {
    __shared__ float4 sbuf[4][2][192];
    __shared__ unsigned smn[4], smx[4];
    const float4* in4 = (const float4*)in;
    float4* gray4 = (float4*)gray;
    const int lane = threadIdx.x & 63;
    const int w = threadIdx.x >> 6;
    const int gw = blockIdx.x * 4 + w;
    const size_t wbase4 = (size_t)gw * 768;
    unsigned mn = 0xFFFFFFFFu, mx = 0u;

#pragma unroll
    for (int k = 0; k < 3; ++k)
        GLOAD_LDS16(in4 + wbase4 + 64 * k + lane, &sbuf[w][0][64 * k]);

#pragma unroll
    for (int t = 0; t < 4; ++t) {
        const int cb = t & 1;
        if (t < 3) {
#pragma unroll
            for (int k = 0; k < 3; ++k)
                GLOAD_LDS16(in4 + wbase4 + (size_t)(t + 1) * 192 + 64 * k + lane,
                            &sbuf[w][cb ^ 1][64 * k]);
            __builtin_amdgcn_s_waitcnt(0x0F73);   // vmcnt(3)
        } else {
            __builtin_amdgcn_s_waitcnt(0x0F71);   // vmcnt(1)
        }
        float4 c0 = sbuf[w][cb][3 * lane + 0];
        float4 c1 = sbuf[w][cb][3 * lane + 1];
        float4 c2 = sbuf[w][cb][3 * lane + 2];
        float g0 = gray1(c0.x, c0.y, c0.z);
        float g1 = gray1(c0.w, c1.x, c1.y);
        float g2 = gray1(c1.z, c1.w, c2.x);
        float g3 = gray1(c2.y, c2.z, c2.w);
        gray4[(size_t)gw * 256 + t * 64 + lane] = make_float4(g0, g1, g2, g3);
        unsigned k0 = fkey(g0), k1 = fkey(g1), k2 = fkey(g2), k3 = fkey(g3);
        mn = min(mn, min(min(k0, k1), min(k2, k3)));
        mx = max(mx, max(max(k0, k1), max(k2, k3)));
    }
    for (int off = 32; off > 0; off >>= 1) {
        mn = min(mn, (unsigned)__shfl_xor((int)mn, off, 64));
        mx = max(mx, (unsigned)__shfl_xor((int)mx, off, 64));
    }
    if (lane == 0) { smn[w] = mn; smx[w] = mx; }
    __syncthreads();
    if (threadIdx.x == 0) {
        mn = min(min(smn[0], smn[1]), min(smn[2], smn[3]));
        mx = max(max(smx[0], smx[1]), max(smx[2], smx[3]));
        atomicMin(&wsu[0], mn);
        atomicMax(&wsu[1], mx);
    }
}

// generic fallback (any size)
__global__ void __launch_bounds__(256)
gray_minmax_generic(const float* __restrict__ in, float* __restrict__ gray,
                    unsigned* __restrict__ wsu, int npix4) {
    __shared__ unsigned smn[4], smx[4];
    const float4* in4 = (const float4*)in;
    const int stride = gridDim.x * blockDim.x;
    unsigned mn = 0xFFFFFFFFu, mx = 0u;
    for (int t = blockIdx.x * blockDim.x + threadIdx.x; t < npix4; t += stride) {
        const float4* p = in4 + (size_t)t * 3;
        float4 c0 = p[0], c1 = p[1], c2 = p[2];
        float g0 = gray1(c0.x, c0.y, c0.z);
        float g1 = gray1(c0.w, c1.x, c1.y);
        float g2 = gray1(c1.z, c1.w, c2.x);
        float g3 = gray1(c2.y, c2.z, c2.w);
        ((float4*)gray)[t] = make_float4(g0, g1, g2, g3);
        unsigned k0 = fkey(g0), k1 = fkey(g1), k2 = fkey(g2), k3 = fkey(g3);
        mn = min(mn, min(min(k0, k1), min(k2, k3)));
        mx = max(mx, max(max(k0, k1), max(k2, k3)));
    }
    for (int off = 32; off > 0; off >>= 1) {
        mn = min(mn, (unsigned)__shfl_xor((int)mn, off, 64));
        mx = max(mx, (unsigned)__shfl_xor((int)mx, off, 64));
    }
    int wave = threadIdx.x >> 6;
    if ((threadIdx.x & 63) == 0) { smn[wave] = mn; smx[wave] = mx; }
    __syncthreads();
    if (threadIdx.x == 0) {
        mn = min(min(smn[0], smn[1]), min(smn[2], smn[3]));
        mx = max(max(smx[0], smx[1]), max(smx[2], smx[3]));
        atomicMin(&wsu[0], mn);
        atomicMax(&wsu[1], mx);
    }
}

// ---------- hist (+ folded edges, + u8 bin codes out) -----------------------
// Wave handles 512 contiguous pixel-groups in 8 rounds: coalesced float4 gray
// loads, coalesced uchar4 code stores, LDS hist, one global add per bin/block.
__global__ void __launch_bounds__(256)
hist_kernel(const float* __restrict__ gray, unsigned char* __restrict__ codes,
            unsigned* __restrict__ wsu, int npix4) {
    __shared__ float eds[257];
    __shared__ unsigned lh[256];
    __shared__ unsigned skey[2];
    if (threadIdx.x == 0) { skey[0] = aload(&wsu[0]); skey[1] = aload(&wsu[1]); }
    __syncthreads();
    const float vmin = keyf(skey[0]);
    const float vmax = keyf(skey[1]);
    const float delta = __fdiv_rn(__fsub_rn(vmax, vmin), 256.0f);
    const float invd = (delta > 0.0f) ? __fdiv_rn(1.0f, delta) : 0.0f;
    if (threadIdx.x < 256)
        eds[threadIdx.x] =
            __fadd_rn(vmin, __fmul_rn((float)threadIdx.x, delta));
    if (threadIdx.x == 0) eds[256] = vmax;
    if (threadIdx.x < 256) lh[threadIdx.x] = 0u;
    __syncthreads();

    const int lane = threadIdx.x & 63;
    const int w = threadIdx.x >> 6;
    const int gw = blockIdx.x * 4 + w;
    const int wbase = gw * 512;
    uchar4* cd4 = (uchar4*)codes;

    auto bin1 = [&](float x) -> int {
        int b = (int)(__fmul_rn(__fsub_rn(x, vmin), invd));
        b = b < 0 ? 0 : (b > 255 ? 255 : b);
        while (b < 255 && x >= eds[b + 1]) ++b;   // exact searchsorted fixup
        while (b > 0 && x < eds[b]) --b;
        return b;
    };

    if (wbase + 512 <= npix4) {
        float4 g[8];
#pragma unroll
        for (int r = 0; r < 8; ++r)
            g[r] = ((const float4*)gray)[wbase + r * 64 + lane];
#pragma unroll
        for (int r = 0; r < 8; ++r) {
            int b0 = bin1(g[r].x), b1 = bin1(g[r].y);
            int b2 = bin1(g[r].z), b3 = bin1(g[r].w);
            atomicAdd(&lh[b0], 1u);
            atomicAdd(&lh[b1], 1u);
            atomicAdd(&lh[b2], 1u);
            atomicAdd(&lh[b3], 1u);
            if (codes)
                cd4[wbase + r * 64 + lane] = make_uchar4(
                    (unsigned char)b0, (unsigned char)b1,
                    (unsigned char)b2, (unsigned char)b3);
        }
    } else {
#pragma unroll
        for (int r = 0; r < 8; ++r) {
            int t = wbase + r * 64 + lane;
            if (t < npix4) {
                float4 g4 = ((const float4*)gray)[t];
                int b0 = bin1(g4.x), b1 = bin1(g4.y);
                int b2 = bin1(g4.z), b3 = bin1(g4.w);
                atomicAdd(&lh[b0], 1u);
                atomicAdd(&lh[b1], 1u);
                atomicAdd(&lh[b2], 1u);
                atomicAdd(&lh[b3], 1u);
                if (codes)
                    cd4[t] = make_uchar4((unsigned char)b0, (unsigned char)b1,
                                         (unsigned char)b2, (unsigned char)b3);
            }
        }
    }
    __syncthreads();
    if (threadIdx.x < 256 && lh[threadIdx.x] != 0u)
        atomicAdd(&wsu[HIST_OFF + threadIdx.x], lh[threadIdx.x]);
}

// ---------- otsu: single block, serial numpy-order scan (R8 structure) ------
__global__ void otsu_kernel(unsigned* __restrict__ wsu, float* __restrict__ wsf) {
    __shared__ float eds[257], histf[256], centers[256], w2a[256], s2a[256];
    int i = threadIdx.x;   // blockDim = 256
    float vmin = keyf(aload(&wsu[0]));
    float vmax = keyf(aload(&wsu[1]));
    float delta = __fdiv_rn(__fsub_rn(vmax, vmin), 256.0f);
    eds[i] = __fadd_rn(vmin, __fmul_rn((float)i, delta));
    if (i == 0) eds[256] = vmax;
    histf[i] = (float)aload(&wsu[HIST_OFF + i]);
    __syncthreads();
    centers[i] = __fmul_rn(__fadd_rn(eds[i], eds[i + 1]), 0.5f);
    __syncthreads();
    if (i == 0) {
        float w = 0.0f, s = 0.0f;
        for (int t = 255; t >= 0; --t) {
            w = __fadd_rn(w, histf[t]);
            s = __fadd_rn(s, __fmul_rn(histf[t], centers[t]));
            w2a[t] = w;
            s2a[t] = s;
        }
        float w1 = 0.0f, s1 = 0.0f, best = -1.0f;
        int bidx = 0;
        for (int t = 0; t < 255; ++t) {
            w1 = __fadd_rn(w1, histf[t]);
            s1 = __fadd_rn(s1, __fmul_rn(histf[t], centers[t]));
            float m1 = __fdiv_rn(s1, fmaxf(w1, 1.0f));
            float m2 = __fdiv_rn(s2a[t + 1], fmaxf(w2a[t + 1], 1.0f));
            float d  = __fsub_rn(m1, m2);
            float v  = __fmul_rn(__fmul_rn(w1, w2a[t + 1]), __fmul_rn(d, d));
            if (v > best) { best = v; bidx = t; }  // first max, like argmax
        }
        wsf[THRESH_OFF] = centers[bidx];
        wsu[BIDX_OFF] = (unsigned)bidx;
    }
}

// ---------- binarize from u8 codes: near write-only --------------------------
// out = (b > bidx) | (b == bidx & gray > thr). Rare gray resolves only for
// pixels in the threshold bin (~0.4%). Unit-stride full-line NT stores (R6).
__global__ void __launch_bounds__(256)
binarize_code(const unsigned char* __restrict__ codes,
              const float* __restrict__ gray, const unsigned* __restrict__ wsu,
              const float* __restrict__ wsf, float* __restrict__ out,
              int npix4) {
    const float thr = wsf[THRESH_OFF];
    const unsigned bidx = wsu[BIDX_OFF];
    const uchar4* cd4 = (const uchar4*)codes;
    const float4* gray4 = (const float4*)gray;
    nfloat4* out4 = (nfloat4*)out;
    const int lane = threadIdx.x & 63;
    const int gw = (blockIdx.x * blockDim.x + threadIdx.x) >> 6;
    const int ma = lane / 3,         qa = lane % 3;
    const int mb = (64 + lane) / 3,  qb = (64 + lane) % 3;
    const int mc = (128 + lane) / 3, qc = (128 + lane) % 3;

    uchar4 c[4];
    bool full[4];
#pragma unroll
    for (int r = 0; r < 4; ++r) {
        int gbase = gw * 256 + r * 64;
        full[r] = (gbase + 64 <= npix4);
        if (full[r] || gbase + lane < npix4) c[r] = cd4[gbase + lane];
    }
#pragma unroll
    for (int r = 0; r < 4; ++r) {
        const int gbase = gw * 256 + r * 64;
        const int t = gbase + lane;
        if (!full[r] && t >= npix4) continue;
        unsigned v0 = c[r].x, v1 = c[r].y, v2 = c[r].z, v3 = c[r].w;
        bool need = (v0 == bidx) | (v1 == bidx) | (v2 == bidx) | (v3 == bidx);
        float4 gg = make_float4(0.f, 0.f, 0.f, 0.f);
        if (need) gg = gray4[t];                  // rare exact resolve
        float b0 = (v0 > bidx) ? 1.0f
                 : ((v0 == bidx && gg.x > thr) ? 1.0f : 0.0f);
        float b1 = (v1 > bidx) ? 1.0f
                 : ((v1 == bidx && gg.y > thr) ? 1.0f : 0.0f);
        float b2 = (v2 > bidx) ? 1.0f
                 : ((v2 == bidx && gg.z > thr) ? 1.0f : 0.0f);
        float b3 = (v3 > bidx) ? 1.0f
                 : ((v3 == bidx && gg.w > thr) ? 1.0f : 0.0f);
        if (full[r]) {
            unsigned u = (b0 != 0.0f ? 1u : 0u) |
                         (b1 != 0.0f ? 0x100u : 0u) |
                         (b2 != 0.0f ? 0x10000u : 0u) |
                         (b3 != 0.0f ? 0x1000000u : 0u);
            const int rb = 3 * gbase;
#pragma unroll
            for (int k = 0; k < 3; ++k) {
                int m = (k == 0) ? ma : (k == 1) ? mb : mc;
                int q = (k == 0) ? qa : (k == 1) ? qb : qc;
                unsigned w = (unsigned)__builtin_amdgcn_ds_bpermute(4 * m,
                                                                    (int)u);
                float h0 = (w & 0xffu)       ? 1.0f : 0.0f;
                float h1 = (w & 0xff00u)     ? 1.0f : 0.0f;
                float h2 = (w & 0xff0000u)   ? 1.0f : 0.0f;
                float h3 = (w & 0xff000000u) ? 1.0f : 0.0f;
                nfloat4 o;
                o.x = (q == 0) ? h0 : (q == 1) ? h1 : h2;
                o.y = (q == 0) ? h0 : (q == 1) ? h1 : h3;
                o.z = (q == 0) ? h0 : (q == 1) ? h2 : h3;
                o.w = (q == 0) ? h1 : (q == 1) ? h2 : h3;
                __builtin_nontemporal_store(o, &out4[rb + 64 * k + lane]);
            }
        } else {
            nfloat4* o = out4 + (size_t)t * 3;
            __builtin_nontemporal_store((nfloat4){b0, b0, b0, b1}, &o[0]);
            __builtin_nontemporal_store((nfloat4){b1, b1, b2, b2}, &o[1]);
            __builtin_nontemporal_store((nfloat4){b2, b3, b3, b3}, &o[2]);
        }
    }
}

// fallback binarize reading gray (R6/R8, proven) if codes don't fit in ws
__global__ void __launch_bounds__(256)
binarize_gray(const float* __restrict__ gray, const float* __restrict__ wsf,
              float* __restrict__ out, int npix4) {
    const float thr = wsf[THRESH_OFF];
    const nfloat4* gray4 = (const nfloat4*)gray;
    nfloat4* out4 = (nfloat4*)out;
    const int lane = threadIdx.x & 63;
    const int gw = (blockIdx.x * blockDim.x + threadIdx.x) >> 6;
    const int ma = lane / 3,         qa = lane % 3;
    const int mb = (64 + lane) / 3,  qb = (64 + lane) % 3;
    const int mc = (128 + lane) / 3, qc = (128 + lane) % 3;
    nfloat4 g[4];
    bool full[4];
#pragma unroll
    for (int r = 0; r < 4; ++r) {
        int gbase = gw * 256 + r * 64;
        full[r] = (gbase + 64 <= npix4);
        if (full[r]) g[r] = gray4[gbase + lane];
    }
#pragma unroll
    for (int r = 0; r < 4; ++r) {
        const int gbase = gw * 256 + r * 64;
        if (full[r]) {
            unsigned u = (g[r].x > thr ? 1u : 0u) |
                         (g[r].y > thr ? 0x100u : 0u) |
                         (g[r].z > thr ? 0x10000u : 0u) |
                         (g[r].w > thr ? 0x1000000u : 0u);
            const int rb = 3 * gbase;
#pragma unroll
            for (int k = 0; k < 3; ++k) {
                int m = (k == 0) ? ma : (k == 1) ? mb : mc;
                int q = (k == 0) ? qa : (k == 1) ? qb : qc;
                unsigned w = (unsigned)__builtin_amdgcn_ds_bpermute(4 * m,
                                                                    (int)u);
                float h0 = (w & 0xffu)       ? 1.0f : 0.0f;
                float h1 = (w & 0xff00u)     ? 1.0f : 0.0f;
                float h2 = (w & 0xff0000u)   ? 1.0f : 0.0f;
                float h3 = (w & 0xff000000u) ? 1.0f : 0.0f;
                nfloat4 o;
                o.x = (q == 0) ? h0 : (q == 1) ? h1 : h2;
                o.y = (q == 0) ? h0 : (q == 1) ? h1 : h3;
                o.z = (q == 0) ? h0 : (q == 1) ? h2 : h3;
                o.w = (q == 0) ? h1 : (q == 1) ? h2 : h3;
                __builtin_nontemporal_store(o, &out4[rb + 64 * k + lane]);
            }
        } else {
            int t = gbase + lane;
            if (t < npix4) {
                nfloat4 gg = gray4[t];
                float b0 = (gg.x > thr) ? 1.0f : 0.0f;
                float b1 = (gg.y > thr) ? 1.0f : 0.0f;
                float b2 = (gg.z > thr) ? 1.0f : 0.0f;
                float b3 = (gg.w > thr) ? 1.0f : 0.0f;
                nfloat4* o = out4 + (size_t)t * 3;
                __builtin_nontemporal_store((nfloat4){b0, b0, b0, b1}, &o[0]);
                __builtin_nontemporal_store((nfloat4){b1, b1, b2, b2}, &o[1]);
                __builtin_nontemporal_store((nfloat4){b2, b3, b3, b3}, &o[2]);
            }
        }
    }
}

extern "C" void kernel_launch(void* const* d_in, const int* in_sizes, int n_in,
                              void* d_out, int out_size, void* d_ws,
                              size_t ws_size, hipStream_t stream) {
    const float* in = (const float*)d_in[0];
    float* out = (float*)d_out;
    int npix  = out_size / 3;
    int npix4 = npix / 4;
    unsigned* wsu = (unsigned*)d_ws;
    float* wsf = (float*)d_ws;
    float* gray = (float*)((char*)d_ws + GRAY_BYTE_OFF);
    size_t codes_off = GRAY_BYTE_OFF + (size_t)npix * sizeof(float);
    unsigned char* codes = (ws_size >= codes_off + (size_t)npix)
                               ? (unsigned char*)d_ws + codes_off
                               : nullptr;

    hipLaunchKernelGGL(init_kernel, dim3(1), dim3(256), 0, stream, wsu);
    if (npix4 % 1024 == 0) {
        hipLaunchKernelGGL(gray_minmax_async, dim3(npix4 / 1024), dim3(256), 0,
                           stream, in, gray, wsu, npix4);
    } else {
        hipLaunchKernelGGL(gray_minmax_generic, dim3(2048), dim3(256), 0,
                           stream, in, gray, wsu, npix4);
    }
    hipLaunchKernelGGL(hist_kernel, dim3((npix4 + 2047) / 2048), dim3(256), 0,
                       stream, gray, codes, wsu, npix4);
    hipLaunchKernelGGL(otsu_kernel, dim3(1), dim3(256), 0, stream, wsu, wsf);
    if (codes) {
        hipLaunchKernelGGL(binarize_code, dim3((npix4 + 1023) / 1024),
                           dim3(256), 0, stream, codes, gray, wsu, wsf, out,
                           npix4);
    } else {
        hipLaunchKernelGGL(binarize_gray, dim3((npix4 + 1023) / 1024),
                           dim3(256), 0, stream, gray, wsf, out, npix4);
    }
}